// Round 1
// baseline (1451.843 us; speedup 1.0000x reference)
//
#include <hip/hip_runtime.h>
#include <math.h>

#define DFEAT 128
#define HDIM 256

// ---------------------------------------------------------------------------
// Kernel 1: batch segment offsets via binary search (batch arrays are sorted).
// offs[b] = first index i with batch[i] >= b, offs[64] = N.
// ---------------------------------------------------------------------------
__global__ void k_offsets(const int* __restrict__ batch1,
                          const int* __restrict__ batch2,
                          int n, int* __restrict__ offs1, int* __restrict__ offs2) {
    int t = threadIdx.x;
    if (t >= 130) return;
    const int* batch = (t < 65) ? batch1 : batch2;
    int b = (t < 65) ? t : t - 65;
    int lo = 0, hi = n;
    while (lo < hi) {
        int mid = (lo + hi) >> 1;
        if (batch[mid] < b) lo = mid + 1; else hi = mid;
    }
    if (t < 65) offs1[b] = lo; else offs2[b] = lo;
}

// ---------------------------------------------------------------------------
// Kernel 2: P = x @ W1[:128,:] + b1   and   Q = x @ W1[128:,:]
// 16 nodes per block, 256 threads (thread j owns output column j).
// ---------------------------------------------------------------------------
__global__ __launch_bounds__(256) void k_pq(const float* __restrict__ x,
                                            const float* __restrict__ W1,
                                            const float* __restrict__ b1,
                                            float* __restrict__ P,
                                            float* __restrict__ Q) {
    __shared__ float xs[16][DFEAT];
    int j = threadIdx.x;
    int n0 = blockIdx.x * 16;
    for (int idx = j; idx < 16 * DFEAT; idx += 256) {
        int r = idx >> 7, c = idx & 127;
        xs[r][c] = x[(size_t)(n0 + r) * DFEAT + c];
    }
    __syncthreads();
    float accP[16], accQ[16];
    float bb = b1[j];
    #pragma unroll
    for (int r = 0; r < 16; ++r) { accP[r] = bb; accQ[r] = 0.f; }
    for (int k = 0; k < DFEAT; ++k) {
        float wt = W1[(size_t)k * HDIM + j];
        float wb = W1[(size_t)(k + DFEAT) * HDIM + j];
        #pragma unroll
        for (int r = 0; r < 16; ++r) {
            float xv = xs[r][k];
            accP[r] = fmaf(xv, wt, accP[r]);
            accQ[r] = fmaf(xv, wb, accQ[r]);
        }
    }
    #pragma unroll
    for (int r = 0; r < 16; ++r) {
        P[(size_t)(n0 + r) * HDIM + j] = accP[r];
        Q[(size_t)(n0 + r) * HDIM + j] = accQ[r];
    }
}

// ---------------------------------------------------------------------------
// Kernel 3: per-edge h = relu(P[src] + Q[tgt]); atomic scatter into Hag[tgt],
// deg[tgt] += 1. One wave (64 lanes) per edge; lane covers 4 columns (float4).
// edge_index layout: row0 = tgt, row1 = src.
// ---------------------------------------------------------------------------
__global__ __launch_bounds__(256) void k_edge(const int* __restrict__ ei,
                                              const float* __restrict__ P,
                                              const float* __restrict__ Q,
                                              float* __restrict__ Hag,
                                              float* __restrict__ deg, int E) {
    int wave = (blockIdx.x * 256 + threadIdx.x) >> 6;
    int lane = threadIdx.x & 63;
    if (wave >= E) return;
    int tgt = ei[wave];
    int src = ei[E + wave];
    const float4* p4 = (const float4*)(P + (size_t)src * HDIM);
    const float4* q4 = (const float4*)(Q + (size_t)tgt * HDIM);
    float4 pv = p4[lane];
    float4 qv = q4[lane];
    float hx = fmaxf(pv.x + qv.x, 0.f);
    float hy = fmaxf(pv.y + qv.y, 0.f);
    float hz = fmaxf(pv.z + qv.z, 0.f);
    float hw = fmaxf(pv.w + qv.w, 0.f);
    float* dst = Hag + (size_t)tgt * HDIM + lane * 4;
    atomicAdd(dst + 0, hx);
    atomicAdd(dst + 1, hy);
    atomicAdd(dst + 2, hz);
    atomicAdd(dst + 3, hw);
    if (lane == 0) atomicAdd(deg + tgt, 1.0f);
}

// ---------------------------------------------------------------------------
// Kernel 4: msg = Hag @ msg_W2 + deg ⊗ b2
// ---------------------------------------------------------------------------
__global__ __launch_bounds__(256) void k_msg(const float* __restrict__ Hag,
                                             const float* __restrict__ W2,
                                             const float* __restrict__ b2,
                                             const float* __restrict__ deg,
                                             float* __restrict__ msg) {
    __shared__ float hs[16][HDIM];
    int j = threadIdx.x;
    int n0 = blockIdx.x * 16;
    for (int idx = j; idx < 16 * HDIM; idx += 256) {
        int r = idx >> 8, c = idx & 255;
        hs[r][c] = Hag[(size_t)(n0 + r) * HDIM + c];
    }
    __syncthreads();
    float acc[16];
    float bb = b2[j];
    #pragma unroll
    for (int r = 0; r < 16; ++r) acc[r] = deg[n0 + r] * bb;
    for (int k = 0; k < HDIM; ++k) {
        float w = W2[(size_t)k * HDIM + j];
        #pragma unroll
        for (int r = 0; r < 16; ++r) acc[r] = fmaf(hs[r][k], w, acc[r]);
    }
    #pragma unroll
    for (int r = 0; r < 16; ++r) msg[(size_t)(n0 + r) * HDIM + j] = acc[r];
}

// ---------------------------------------------------------------------------
// Kernel 5: block-diagonal masked attention (flash-style, per-batch spans).
// attn[i] = xq[i] - softmax_row(xq_b @ xk_b^T) @ xk_b.
// One wave per query row; supports span width nk <= 512.
// ---------------------------------------------------------------------------
__global__ __launch_bounds__(256) void k_attn(const float* __restrict__ xq,
                                              const float* __restrict__ xk,
                                              const int* __restrict__ offsq,
                                              const int* __restrict__ offsk,
                                              float* __restrict__ attn) {
    int b = blockIdx.x;
    int part = blockIdx.y;
    int q0 = offsq[b], q1 = offsq[b + 1];
    int k0 = offsk[b], k1 = offsk[b + 1];
    int nk = k1 - k0;
    int wave = threadIdx.x >> 6, lane = threadIdx.x & 63;
    __shared__ float qrow[4][DFEAT];
    __shared__ float pw[4][512];
    int stride = 4 * gridDim.y;
    for (int i = q0 + part * 4 + wave; i < q1; i += stride) {
        if (nk == 0) {  // degenerate (never happens with these sizes)
            attn[(size_t)i * DFEAT + lane] = xq[(size_t)i * DFEAT + lane];
            attn[(size_t)i * DFEAT + 64 + lane] = xq[(size_t)i * DFEAT + 64 + lane];
            continue;
        }
        // stage query row in LDS (wave-private region)
        qrow[wave][lane]      = xq[(size_t)i * DFEAT + lane];
        qrow[wave][lane + 64] = xq[(size_t)i * DFEAT + 64 + lane];
        asm volatile("s_waitcnt lgkmcnt(0)" ::: "memory");
        // scores for this lane's columns (static-indexed to stay in regs)
        float s[8];
        float m = -1e30f;
        #pragma unroll
        for (int u = 0; u < 8; ++u) {
            int c = lane + u * 64;
            if (c < nk) {
                const float4* krow = (const float4*)(xk + (size_t)(k0 + c) * DFEAT);
                float dot = 0.f;
                #pragma unroll
                for (int d4 = 0; d4 < 32; ++d4) {
                    float4 kv = krow[d4];
                    dot = fmaf(kv.x, qrow[wave][d4 * 4 + 0], dot);
                    dot = fmaf(kv.y, qrow[wave][d4 * 4 + 1], dot);
                    dot = fmaf(kv.z, qrow[wave][d4 * 4 + 2], dot);
                    dot = fmaf(kv.w, qrow[wave][d4 * 4 + 3], dot);
                }
                s[u] = dot;
                m = fmaxf(m, dot);
            } else {
                s[u] = -1e30f;
            }
        }
        #pragma unroll
        for (int off = 32; off; off >>= 1) m = fmaxf(m, __shfl_xor(m, off));
        float e[8];
        float lsum = 0.f;
        #pragma unroll
        for (int u = 0; u < 8; ++u) { e[u] = expf(s[u] - m); lsum += e[u]; }
        #pragma unroll
        for (int off = 32; off; off >>= 1) lsum += __shfl_xor(lsum, off);
        float inv = 1.0f / lsum;
        #pragma unroll
        for (int u = 0; u < 8; ++u) {
            int c = lane + u * 64;
            if (c < nk) pw[wave][c] = e[u] * inv;
        }
        asm volatile("s_waitcnt lgkmcnt(0)" ::: "memory");
        // weighted sum over keys: lane owns output cols {lane, lane+64}
        float a0 = 0.f, a1 = 0.f;
        for (int c = 0; c < nk; ++c) {
            float p = pw[wave][c];
            a0 = fmaf(p, xk[(size_t)(k0 + c) * DFEAT + lane], a0);
            a1 = fmaf(p, xk[(size_t)(k0 + c) * DFEAT + 64 + lane], a1);
        }
        attn[(size_t)i * DFEAT + lane]      = xq[(size_t)i * DFEAT + lane] - a0;
        attn[(size_t)i * DFEAT + 64 + lane] = xq[(size_t)i * DFEAT + 64 + lane] - a1;
    }
}

// ---------------------------------------------------------------------------
// Kernel 6: fused node update:
// out = x + relu([msg, attn, x] @ upd_W1 + upd_b1) @ upd_W2 + upd_b2
// 16 nodes per block, 256 threads.
// ---------------------------------------------------------------------------
__global__ __launch_bounds__(256) void k_update(const float* __restrict__ x,
                                                const float* __restrict__ msg,
                                                const float* __restrict__ attn,
                                                const float* __restrict__ W1,
                                                const float* __restrict__ b1,
                                                const float* __restrict__ W2,
                                                const float* __restrict__ b2,
                                                float* __restrict__ out) {
    __shared__ float us[16][512];
    __shared__ float hs[16][HDIM];
    int j = threadIdx.x;
    int n0 = blockIdx.x * 16;
    for (int idx = j; idx < 16 * 512; idx += 256) {
        int r = idx >> 9, c = idx & 511;
        int node = n0 + r;
        float v;
        if (c < 256)      v = msg[(size_t)node * HDIM + c];
        else if (c < 384) v = attn[(size_t)node * DFEAT + (c - 256)];
        else              v = x[(size_t)node * DFEAT + (c - 384)];
        us[r][c] = v;
    }
    __syncthreads();
    float acc[16];
    float bb = b1[j];
    #pragma unroll
    for (int r = 0; r < 16; ++r) acc[r] = bb;
    for (int k = 0; k < 512; ++k) {
        float w = W1[(size_t)k * HDIM + j];
        #pragma unroll
        for (int r = 0; r < 16; ++r) acc[r] = fmaf(us[r][k], w, acc[r]);
    }
    #pragma unroll
    for (int r = 0; r < 16; ++r) hs[r][j] = fmaxf(acc[r], 0.f);
    __syncthreads();
    int c = j & 127, g = j >> 7;           // 2 groups x 8 nodes
    float acc2[8];
    float b2v = b2[c];
    #pragma unroll
    for (int r = 0; r < 8; ++r) acc2[r] = b2v;
    for (int k = 0; k < HDIM; ++k) {
        float w = W2[(size_t)k * DFEAT + c];
        #pragma unroll
        for (int r = 0; r < 8; ++r) acc2[r] = fmaf(hs[g * 8 + r][k], w, acc2[r]);
    }
    #pragma unroll
    for (int r = 0; r < 8; ++r) {
        int node = n0 + g * 8 + r;
        out[(size_t)node * DFEAT + c] = x[(size_t)node * DFEAT + c] + acc2[r];
    }
}

// ---------------------------------------------------------------------------
extern "C" void kernel_launch(void* const* d_in, const int* in_sizes, int n_in,
                              void* d_out, int out_size, void* d_ws, size_t ws_size,
                              hipStream_t stream) {
    const float* x1     = (const float*)d_in[0];
    const int*   ei1    = (const int*)d_in[1];
    const int*   batch1 = (const int*)d_in[2];
    const float* x2     = (const float*)d_in[3];
    const int*   ei2    = (const int*)d_in[4];
    const int*   batch2 = (const int*)d_in[5];
    const float* msg_W1 = (const float*)d_in[6];
    const float* msg_b1 = (const float*)d_in[7];
    const float* msg_W2 = (const float*)d_in[8];
    const float* msg_b2 = (const float*)d_in[9];
    const float* upd_W1 = (const float*)d_in[10];
    const float* upd_b1 = (const float*)d_in[11];
    const float* upd_W2 = (const float*)d_in[12];
    const float* upd_b2 = (const float*)d_in[13];

    const int N = in_sizes[0] / DFEAT;   // 8192
    const int E = in_sizes[1] / 2;       // 131072

    char* base = (char*)d_ws;
    int* offs1 = (int*)base;
    int* offs2 = offs1 + 128;
    float* F = (float*)(base + 1024);
    size_t NH = (size_t)N * HDIM;
    size_t ND = (size_t)N * DFEAT;
    float* P1    = F;
    float* Q1    = P1 + NH;
    float* P2    = Q1 + NH;
    float* Q2    = P2 + NH;
    float* msg1  = Q2 + NH;
    float* msg2  = msg1 + NH;
    float* attn1 = msg2 + NH;
    float* attn2 = attn1 + ND;
    float* Hag1  = attn2 + ND;
    float* Hag2  = Hag1 + NH;
    float* deg1  = Hag2 + NH;
    float* deg2  = deg1 + N;

    // zero the atomic-accumulated buffers (ws is poisoned before every call)
    hipMemsetAsync(Hag1, 0, (2 * NH + 2 * (size_t)N) * sizeof(float), stream);

    k_offsets<<<1, 192, 0, stream>>>(batch1, batch2, N, offs1, offs2);

    k_pq<<<N / 16, 256, 0, stream>>>(x1, msg_W1, msg_b1, P1, Q1);
    k_pq<<<N / 16, 256, 0, stream>>>(x2, msg_W1, msg_b1, P2, Q2);

    k_edge<<<E / 4, 256, 0, stream>>>(ei1, P1, Q1, Hag1, deg1, E);
    k_edge<<<E / 4, 256, 0, stream>>>(ei2, P2, Q2, Hag2, deg2, E);

    k_msg<<<N / 16, 256, 0, stream>>>(Hag1, msg_W2, msg_b2, deg1, msg1);
    k_msg<<<N / 16, 256, 0, stream>>>(Hag2, msg_W2, msg_b2, deg2, msg2);

    dim3 ag(64, 8);
    k_attn<<<ag, 256, 0, stream>>>(x1, x2, offs1, offs2, attn1);
    k_attn<<<ag, 256, 0, stream>>>(x2, x1, offs2, offs1, attn2);

    float* out1 = (float*)d_out;
    float* out2 = out1 + ND;
    k_update<<<N / 16, 256, 0, stream>>>(x1, msg1, attn1, upd_W1, upd_b1, upd_W2, upd_b2, out1);
    k_update<<<N / 16, 256, 0, stream>>>(x2, msg2, attn2, upd_W1, upd_b1, upd_W2, upd_b2, out2);
}

// Round 2
// 615.088 us; speedup vs baseline: 2.3604x; 2.3604x over previous
//
#include <hip/hip_runtime.h>
#include <math.h>

#define DFEAT 128
#define HDIM 256

// ---------------------------------------------------------------------------
// Kernel 1: batch segment offsets via binary search (batch arrays are sorted).
// ---------------------------------------------------------------------------
__global__ void k_offsets(const int* __restrict__ batch1,
                          const int* __restrict__ batch2,
                          int n, int* __restrict__ offs1, int* __restrict__ offs2) {
    int t = threadIdx.x;
    if (t >= 130) return;
    const int* batch = (t < 65) ? batch1 : batch2;
    int b = (t < 65) ? t : t - 65;
    int lo = 0, hi = n;
    while (lo < hi) {
        int mid = (lo + hi) >> 1;
        if (batch[mid] < b) lo = mid + 1; else hi = mid;
    }
    if (t < 65) offs1[b] = lo; else offs2[b] = lo;
}

// ---------------------------------------------------------------------------
// Kernel 2: P = x @ W1[:128,:] + b1   and   Q = x @ W1[128:,:]
// ---------------------------------------------------------------------------
__global__ __launch_bounds__(256) void k_pq(const float* __restrict__ x,
                                            const float* __restrict__ W1,
                                            const float* __restrict__ b1,
                                            float* __restrict__ P,
                                            float* __restrict__ Q) {
    __shared__ float xs[16][DFEAT];
    int j = threadIdx.x;
    int n0 = blockIdx.x * 16;
    for (int idx = j; idx < 16 * DFEAT; idx += 256) {
        int r = idx >> 7, c = idx & 127;
        xs[r][c] = x[(size_t)(n0 + r) * DFEAT + c];
    }
    __syncthreads();
    float accP[16], accQ[16];
    float bb = b1[j];
    #pragma unroll
    for (int r = 0; r < 16; ++r) { accP[r] = bb; accQ[r] = 0.f; }
    for (int k = 0; k < DFEAT; ++k) {
        float wt = W1[(size_t)k * HDIM + j];
        float wb = W1[(size_t)(k + DFEAT) * HDIM + j];
        #pragma unroll
        for (int r = 0; r < 16; ++r) {
            float xv = xs[r][k];
            accP[r] = fmaf(xv, wt, accP[r]);
            accQ[r] = fmaf(xv, wb, accQ[r]);
        }
    }
    #pragma unroll
    for (int r = 0; r < 16; ++r) {
        P[(size_t)(n0 + r) * HDIM + j] = accP[r];
        Q[(size_t)(n0 + r) * HDIM + j] = accQ[r];
    }
}

// ---------------------------------------------------------------------------
// Kernel 3a: degree histogram for both graphs (int atomics, 4B each — cheap).
// edge_index layout: row0 = tgt, row1 = src.
// ---------------------------------------------------------------------------
__global__ __launch_bounds__(256) void k_hist(const int* __restrict__ ei1,
                                              const int* __restrict__ ei2,
                                              int E,
                                              int* __restrict__ deg1,
                                              int* __restrict__ deg2) {
    int t = blockIdx.x * 256 + threadIdx.x;
    if (t < E) {
        atomicAdd(deg1 + ei1[t], 1);
    } else if (t < 2 * E) {
        atomicAdd(deg2 + ei2[t - E], 1);
    }
}

// ---------------------------------------------------------------------------
// Kernel 3b: exclusive scan of degrees -> CSR offsets + scatter cursors.
// One block per graph, 256 threads, 32 elems/thread (N=8192).
// ---------------------------------------------------------------------------
__global__ __launch_bounds__(256) void k_scan(const int* __restrict__ deg1,
                                              const int* __restrict__ deg2,
                                              int N,
                                              int* __restrict__ offs1, int* __restrict__ cur1,
                                              int* __restrict__ offs2, int* __restrict__ cur2) {
    const int* deg = blockIdx.x ? deg2 : deg1;
    int* offs = blockIdx.x ? offs2 : offs1;
    int* cur  = blockIdx.x ? cur2  : cur1;
    int t = threadIdx.x;
    int base = t * 32;
    int vals[32];
    int run = 0;
    #pragma unroll
    for (int i = 0; i < 32; ++i) { vals[i] = run; run += deg[base + i]; }
    __shared__ int tot[256];
    tot[t] = run;
    __syncthreads();
    for (int off = 1; off < 256; off <<= 1) {
        int v = (t >= off) ? tot[t - off] : 0;
        __syncthreads();
        tot[t] += v;
        __syncthreads();
    }
    int prefix = (t == 0) ? 0 : tot[t - 1];
    #pragma unroll
    for (int i = 0; i < 32; ++i) {
        int o = prefix + vals[i];
        offs[base + i] = o;
        cur[base + i] = o;
    }
    if (t == 255) offs[N] = tot[255];
}

// ---------------------------------------------------------------------------
// Kernel 3c: scatter src ids into per-target buckets (CSR adjacency).
// ---------------------------------------------------------------------------
__global__ __launch_bounds__(256) void k_scatter(const int* __restrict__ ei1,
                                                 const int* __restrict__ ei2,
                                                 int E,
                                                 int* __restrict__ cur1, int* __restrict__ srcb1,
                                                 int* __restrict__ cur2, int* __restrict__ srcb2) {
    int t = blockIdx.x * 256 + threadIdx.x;
    if (t < E) {
        int tgt = ei1[t], src = ei1[E + t];
        int pos = atomicAdd(cur1 + tgt, 1);
        srcb1[pos] = src;
    } else if (t < 2 * E) {
        int e = t - E;
        int tgt = ei2[e], src = ei2[E + e];
        int pos = atomicAdd(cur2 + tgt, 1);
        srcb2[pos] = src;
    }
}

// ---------------------------------------------------------------------------
// Kernel 3d: gather-aggregate. One wave per target node:
// Hag[n] = sum_{e in CSR(n)} relu(P[src_e] + Q[n]).  Single write, no atomics.
// ---------------------------------------------------------------------------
__global__ __launch_bounds__(256) void k_aggr(const float* __restrict__ P,
                                              const float* __restrict__ Q,
                                              const int* __restrict__ offs,
                                              const int* __restrict__ srcb,
                                              float* __restrict__ Hag, int N) {
    int w = (blockIdx.x * 256 + threadIdx.x) >> 6;
    int lane = threadIdx.x & 63;
    if (w >= N) return;
    float4 q = ((const float4*)(Q + (size_t)w * HDIM))[lane];
    int e0 = offs[w], e1 = offs[w + 1];
    float4 acc = {0.f, 0.f, 0.f, 0.f};
    int e = e0;
    for (; e + 1 < e1; e += 2) {
        int s0 = srcb[e];
        int s1 = srcb[e + 1];
        float4 pa = ((const float4*)(P + (size_t)s0 * HDIM))[lane];
        float4 pb = ((const float4*)(P + (size_t)s1 * HDIM))[lane];
        acc.x += fmaxf(pa.x + q.x, 0.f) + fmaxf(pb.x + q.x, 0.f);
        acc.y += fmaxf(pa.y + q.y, 0.f) + fmaxf(pb.y + q.y, 0.f);
        acc.z += fmaxf(pa.z + q.z, 0.f) + fmaxf(pb.z + q.z, 0.f);
        acc.w += fmaxf(pa.w + q.w, 0.f) + fmaxf(pb.w + q.w, 0.f);
    }
    if (e < e1) {
        int s0 = srcb[e];
        float4 pa = ((const float4*)(P + (size_t)s0 * HDIM))[lane];
        acc.x += fmaxf(pa.x + q.x, 0.f);
        acc.y += fmaxf(pa.y + q.y, 0.f);
        acc.z += fmaxf(pa.z + q.z, 0.f);
        acc.w += fmaxf(pa.w + q.w, 0.f);
    }
    ((float4*)(Hag + (size_t)w * HDIM))[lane] = acc;
}

// ---------------------------------------------------------------------------
// Kernel 4: msg = Hag @ msg_W2 + deg ⊗ b2
// ---------------------------------------------------------------------------
__global__ __launch_bounds__(256) void k_msg(const float* __restrict__ Hag,
                                             const float* __restrict__ W2,
                                             const float* __restrict__ b2,
                                             const int* __restrict__ deg,
                                             float* __restrict__ msg) {
    __shared__ float hs[16][HDIM];
    int j = threadIdx.x;
    int n0 = blockIdx.x * 16;
    for (int idx = j; idx < 16 * HDIM; idx += 256) {
        int r = idx >> 8, c = idx & 255;
        hs[r][c] = Hag[(size_t)(n0 + r) * HDIM + c];
    }
    __syncthreads();
    float acc[16];
    float bb = b2[j];
    #pragma unroll
    for (int r = 0; r < 16; ++r) acc[r] = (float)deg[n0 + r] * bb;
    for (int k = 0; k < HDIM; ++k) {
        float w = W2[(size_t)k * HDIM + j];
        #pragma unroll
        for (int r = 0; r < 16; ++r) acc[r] = fmaf(hs[r][k], w, acc[r]);
    }
    #pragma unroll
    for (int r = 0; r < 16; ++r) msg[(size_t)(n0 + r) * HDIM + j] = acc[r];
}

// ---------------------------------------------------------------------------
// Kernel 5: block-diagonal masked attention (per-batch spans, sorted batches).
// attn[i] = xq[i] - softmax_row(xq_b @ xk_b^T) @ xk_b.  One wave per query row.
// ---------------------------------------------------------------------------
__global__ __launch_bounds__(256) void k_attn(const float* __restrict__ xq,
                                              const float* __restrict__ xk,
                                              const int* __restrict__ offsq,
                                              const int* __restrict__ offsk,
                                              float* __restrict__ attn) {
    int b = blockIdx.x;
    int part = blockIdx.y;
    int q0 = offsq[b], q1 = offsq[b + 1];
    int k0 = offsk[b], k1 = offsk[b + 1];
    int nk = k1 - k0;
    int wave = threadIdx.x >> 6, lane = threadIdx.x & 63;
    __shared__ float qrow[4][DFEAT];
    __shared__ float pw[4][512];
    int stride = 4 * gridDim.y;
    for (int i = q0 + part * 4 + wave; i < q1; i += stride) {
        if (nk == 0) {
            attn[(size_t)i * DFEAT + lane] = xq[(size_t)i * DFEAT + lane];
            attn[(size_t)i * DFEAT + 64 + lane] = xq[(size_t)i * DFEAT + 64 + lane];
            continue;
        }
        qrow[wave][lane]      = xq[(size_t)i * DFEAT + lane];
        qrow[wave][lane + 64] = xq[(size_t)i * DFEAT + 64 + lane];
        asm volatile("s_waitcnt lgkmcnt(0)" ::: "memory");
        float s[8];
        float m = -1e30f;
        #pragma unroll
        for (int u = 0; u < 8; ++u) {
            int c = lane + u * 64;
            if (c < nk) {
                const float4* krow = (const float4*)(xk + (size_t)(k0 + c) * DFEAT);
                float dot = 0.f;
                #pragma unroll
                for (int d4 = 0; d4 < 32; ++d4) {
                    float4 kv = krow[d4];
                    dot = fmaf(kv.x, qrow[wave][d4 * 4 + 0], dot);
                    dot = fmaf(kv.y, qrow[wave][d4 * 4 + 1], dot);
                    dot = fmaf(kv.z, qrow[wave][d4 * 4 + 2], dot);
                    dot = fmaf(kv.w, qrow[wave][d4 * 4 + 3], dot);
                }
                s[u] = dot;
                m = fmaxf(m, dot);
            } else {
                s[u] = -1e30f;
            }
        }
        #pragma unroll
        for (int off = 32; off; off >>= 1) m = fmaxf(m, __shfl_xor(m, off));
        float e[8];
        float lsum = 0.f;
        #pragma unroll
        for (int u = 0; u < 8; ++u) { e[u] = expf(s[u] - m); lsum += e[u]; }
        #pragma unroll
        for (int off = 32; off; off >>= 1) lsum += __shfl_xor(lsum, off);
        float inv = 1.0f / lsum;
        #pragma unroll
        for (int u = 0; u < 8; ++u) {
            int c = lane + u * 64;
            if (c < nk) pw[wave][c] = e[u] * inv;
        }
        asm volatile("s_waitcnt lgkmcnt(0)" ::: "memory");
        float a0 = 0.f, a1 = 0.f;
        for (int c = 0; c < nk; ++c) {
            float p = pw[wave][c];
            a0 = fmaf(p, xk[(size_t)(k0 + c) * DFEAT + lane], a0);
            a1 = fmaf(p, xk[(size_t)(k0 + c) * DFEAT + 64 + lane], a1);
        }
        attn[(size_t)i * DFEAT + lane]      = xq[(size_t)i * DFEAT + lane] - a0;
        attn[(size_t)i * DFEAT + 64 + lane] = xq[(size_t)i * DFEAT + 64 + lane] - a1;
    }
}

// ---------------------------------------------------------------------------
// Kernel 6: fused node update:
// out = x + relu([msg, attn, x] @ upd_W1 + upd_b1) @ upd_W2 + upd_b2
// ---------------------------------------------------------------------------
__global__ __launch_bounds__(256) void k_update(const float* __restrict__ x,
                                                const float* __restrict__ msg,
                                                const float* __restrict__ attn,
                                                const float* __restrict__ W1,
                                                const float* __restrict__ b1,
                                                const float* __restrict__ W2,
                                                const float* __restrict__ b2,
                                                float* __restrict__ out) {
    __shared__ float us[16][512];
    __shared__ float hs[16][HDIM];
    int j = threadIdx.x;
    int n0 = blockIdx.x * 16;
    for (int idx = j; idx < 16 * 512; idx += 256) {
        int r = idx >> 9, c = idx & 511;
        int node = n0 + r;
        float v;
        if (c < 256)      v = msg[(size_t)node * HDIM + c];
        else if (c < 384) v = attn[(size_t)node * DFEAT + (c - 256)];
        else              v = x[(size_t)node * DFEAT + (c - 384)];
        us[r][c] = v;
    }
    __syncthreads();
    float acc[16];
    float bb = b1[j];
    #pragma unroll
    for (int r = 0; r < 16; ++r) acc[r] = bb;
    for (int k = 0; k < 512; ++k) {
        float w = W1[(size_t)k * HDIM + j];
        #pragma unroll
        for (int r = 0; r < 16; ++r) acc[r] = fmaf(us[r][k], w, acc[r]);
    }
    #pragma unroll
    for (int r = 0; r < 16; ++r) hs[r][j] = fmaxf(acc[r], 0.f);
    __syncthreads();
    int c = j & 127, g = j >> 7;
    float acc2[8];
    float b2v = b2[c];
    #pragma unroll
    for (int r = 0; r < 8; ++r) acc2[r] = b2v;
    for (int k = 0; k < HDIM; ++k) {
        float w = W2[(size_t)k * DFEAT + c];
        #pragma unroll
        for (int r = 0; r < 8; ++r) acc2[r] = fmaf(hs[g * 8 + r][k], w, acc2[r]);
    }
    #pragma unroll
    for (int r = 0; r < 8; ++r) {
        int node = n0 + g * 8 + r;
        out[(size_t)node * DFEAT + c] = x[(size_t)node * DFEAT + c] + acc2[r];
    }
}

// ---------------------------------------------------------------------------
extern "C" void kernel_launch(void* const* d_in, const int* in_sizes, int n_in,
                              void* d_out, int out_size, void* d_ws, size_t ws_size,
                              hipStream_t stream) {
    const float* x1     = (const float*)d_in[0];
    const int*   ei1    = (const int*)d_in[1];
    const int*   batch1 = (const int*)d_in[2];
    const float* x2     = (const float*)d_in[3];
    const int*   ei2    = (const int*)d_in[4];
    const int*   batch2 = (const int*)d_in[5];
    const float* msg_W1 = (const float*)d_in[6];
    const float* msg_b1 = (const float*)d_in[7];
    const float* msg_W2 = (const float*)d_in[8];
    const float* msg_b2 = (const float*)d_in[9];
    const float* upd_W1 = (const float*)d_in[10];
    const float* upd_b1 = (const float*)d_in[11];
    const float* upd_W2 = (const float*)d_in[12];
    const float* upd_b2 = (const float*)d_in[13];

    const int N = in_sizes[0] / DFEAT;   // 8192
    const int E = in_sizes[1] / 2;       // 131072

    char* base = (char*)d_ws;
    // int region
    int* offs1   = (int*)base;                 // 65
    int* offs2   = offs1 + 128;                // 65
    int* deg1    = offs2 + 128;                // N
    int* deg2    = deg1 + N;                   // N
    int* coffs1  = deg2 + N;                   // N+1
    int* coffs2  = coffs1 + (N + 64);          // N+1
    int* cur1    = coffs2 + (N + 64);          // N
    int* cur2    = cur1 + N;                   // N
    int* srcb1   = cur2 + N;                   // E
    int* srcb2   = srcb1 + E;                  // E
    float* F = (float*)(srcb2 + E);
    size_t NH = (size_t)N * HDIM;
    size_t ND = (size_t)N * DFEAT;
    float* P1    = F;
    float* Q1    = P1 + NH;
    float* P2    = Q1 + NH;
    float* Q2    = P2 + NH;
    float* msg1  = Q2 + NH;
    float* msg2  = msg1 + NH;
    float* attn1 = msg2 + NH;
    float* attn2 = attn1 + ND;
    float* Hag1  = attn2 + ND;
    float* Hag2  = Hag1 + NH;

    // zero only the degree histograms (64 KB)
    hipMemsetAsync(deg1, 0, 2 * (size_t)N * sizeof(int), stream);

    k_offsets<<<1, 192, 0, stream>>>(batch1, batch2, N, offs1, offs2);

    k_hist<<<(2 * E + 255) / 256, 256, 0, stream>>>(ei1, ei2, E, deg1, deg2);
    k_scan<<<2, 256, 0, stream>>>(deg1, deg2, N, coffs1, cur1, coffs2, cur2);
    k_scatter<<<(2 * E + 255) / 256, 256, 0, stream>>>(ei1, ei2, E, cur1, srcb1, cur2, srcb2);

    k_pq<<<N / 16, 256, 0, stream>>>(x1, msg_W1, msg_b1, P1, Q1);
    k_pq<<<N / 16, 256, 0, stream>>>(x2, msg_W1, msg_b1, P2, Q2);

    k_aggr<<<N / 4, 256, 0, stream>>>(P1, Q1, coffs1, srcb1, Hag1, N);
    k_aggr<<<N / 4, 256, 0, stream>>>(P2, Q2, coffs2, srcb2, Hag2, N);

    k_msg<<<N / 16, 256, 0, stream>>>(Hag1, msg_W2, msg_b2, deg1, msg1);
    k_msg<<<N / 16, 256, 0, stream>>>(Hag2, msg_W2, msg_b2, deg2, msg2);

    dim3 ag(64, 8);
    k_attn<<<ag, 256, 0, stream>>>(x1, x2, offs1, offs2, attn1);
    k_attn<<<ag, 256, 0, stream>>>(x2, x1, offs2, offs1, attn2);

    float* out1 = (float*)d_out;
    float* out2 = out1 + ND;
    k_update<<<N / 16, 256, 0, stream>>>(x1, msg1, attn1, upd_W1, upd_b1, upd_W2, upd_b2, out1);
    k_update<<<N / 16, 256, 0, stream>>>(x2, msg2, attn2, upd_W1, upd_b1, upd_W2, upd_b2, out2);
}

// Round 3
// 471.861 us; speedup vs baseline: 3.0768x; 1.3035x over previous
//
#include <hip/hip_runtime.h>
#include <math.h>

#define DFEAT 128
#define HDIM 256

// ---------------------------------------------------------------------------
// Kernel 1: batch segment offsets via binary search (batch arrays are sorted).
// ---------------------------------------------------------------------------
__global__ void k_offsets(const int* __restrict__ batch1,
                          const int* __restrict__ batch2,
                          int n, int* __restrict__ offs1, int* __restrict__ offs2) {
    int t = threadIdx.x;
    if (t >= 130) return;
    const int* batch = (t < 65) ? batch1 : batch2;
    int b = (t < 65) ? t : t - 65;
    int lo = 0, hi = n;
    while (lo < hi) {
        int mid = (lo + hi) >> 1;
        if (batch[mid] < b) lo = mid + 1; else hi = mid;
    }
    if (t < 65) offs1[b] = lo; else offs2[b] = lo;
}

// ---------------------------------------------------------------------------
// Kernel 2: P = x @ W1[:128,:] + b1   and   Q = x @ W1[128:,:]
// ---------------------------------------------------------------------------
__global__ __launch_bounds__(256) void k_pq(const float* __restrict__ x,
                                            const float* __restrict__ W1,
                                            const float* __restrict__ b1,
                                            float* __restrict__ P,
                                            float* __restrict__ Q) {
    __shared__ float xs[16][DFEAT];
    int j = threadIdx.x;
    int n0 = blockIdx.x * 16;
    for (int idx = j; idx < 16 * DFEAT; idx += 256) {
        int r = idx >> 7, c = idx & 127;
        xs[r][c] = x[(size_t)(n0 + r) * DFEAT + c];
    }
    __syncthreads();
    float accP[16], accQ[16];
    float bb = b1[j];
    #pragma unroll
    for (int r = 0; r < 16; ++r) { accP[r] = bb; accQ[r] = 0.f; }
    for (int k = 0; k < DFEAT; ++k) {
        float wt = W1[(size_t)k * HDIM + j];
        float wb = W1[(size_t)(k + DFEAT) * HDIM + j];
        #pragma unroll
        for (int r = 0; r < 16; ++r) {
            float xv = xs[r][k];
            accP[r] = fmaf(xv, wt, accP[r]);
            accQ[r] = fmaf(xv, wb, accQ[r]);
        }
    }
    #pragma unroll
    for (int r = 0; r < 16; ++r) {
        P[(size_t)(n0 + r) * HDIM + j] = accP[r];
        Q[(size_t)(n0 + r) * HDIM + j] = accQ[r];
    }
}

// ---------------------------------------------------------------------------
// Kernel 3a: degree histogram (int atomics).
// ---------------------------------------------------------------------------
__global__ __launch_bounds__(256) void k_hist(const int* __restrict__ ei1,
                                              const int* __restrict__ ei2,
                                              int E,
                                              int* __restrict__ deg1,
                                              int* __restrict__ deg2) {
    int t = blockIdx.x * 256 + threadIdx.x;
    if (t < E) {
        atomicAdd(deg1 + ei1[t], 1);
    } else if (t < 2 * E) {
        atomicAdd(deg2 + ei2[t - E], 1);
    }
}

// ---------------------------------------------------------------------------
// Kernel 3b: exclusive scan of degrees -> CSR offsets + scatter cursors.
// ---------------------------------------------------------------------------
__global__ __launch_bounds__(256) void k_scan(const int* __restrict__ deg1,
                                              const int* __restrict__ deg2,
                                              int N,
                                              int* __restrict__ offs1, int* __restrict__ cur1,
                                              int* __restrict__ offs2, int* __restrict__ cur2) {
    const int* deg = blockIdx.x ? deg2 : deg1;
    int* offs = blockIdx.x ? offs2 : offs1;
    int* cur  = blockIdx.x ? cur2  : cur1;
    int t = threadIdx.x;
    int base = t * 32;
    int vals[32];
    int run = 0;
    #pragma unroll
    for (int i = 0; i < 32; ++i) { vals[i] = run; run += deg[base + i]; }
    __shared__ int tot[256];
    tot[t] = run;
    __syncthreads();
    for (int off = 1; off < 256; off <<= 1) {
        int v = (t >= off) ? tot[t - off] : 0;
        __syncthreads();
        tot[t] += v;
        __syncthreads();
    }
    int prefix = (t == 0) ? 0 : tot[t - 1];
    #pragma unroll
    for (int i = 0; i < 32; ++i) {
        int o = prefix + vals[i];
        offs[base + i] = o;
        cur[base + i] = o;
    }
    if (t == 255) offs[N] = tot[255];
}

// ---------------------------------------------------------------------------
// Kernel 3c: scatter src ids into per-target buckets (CSR adjacency).
// ---------------------------------------------------------------------------
__global__ __launch_bounds__(256) void k_scatter(const int* __restrict__ ei1,
                                                 const int* __restrict__ ei2,
                                                 int E,
                                                 int* __restrict__ cur1, int* __restrict__ srcb1,
                                                 int* __restrict__ cur2, int* __restrict__ srcb2) {
    int t = blockIdx.x * 256 + threadIdx.x;
    if (t < E) {
        int tgt = ei1[t], src = ei1[E + t];
        int pos = atomicAdd(cur1 + tgt, 1);
        srcb1[pos] = src;
    } else if (t < 2 * E) {
        int e = t - E;
        int tgt = ei2[e], src = ei2[E + e];
        int pos = atomicAdd(cur2 + tgt, 1);
        srcb2[pos] = src;
    }
}

// ---------------------------------------------------------------------------
// Kernel 3d: gather-aggregate. One wave per target node.
// ---------------------------------------------------------------------------
__global__ __launch_bounds__(256) void k_aggr(const float* __restrict__ P,
                                              const float* __restrict__ Q,
                                              const int* __restrict__ offs,
                                              const int* __restrict__ srcb,
                                              float* __restrict__ Hag, int N) {
    int w = (blockIdx.x * 256 + threadIdx.x) >> 6;
    int lane = threadIdx.x & 63;
    if (w >= N) return;
    float4 q = ((const float4*)(Q + (size_t)w * HDIM))[lane];
    int e0 = offs[w], e1 = offs[w + 1];
    float4 acc = {0.f, 0.f, 0.f, 0.f};
    int e = e0;
    for (; e + 1 < e1; e += 2) {
        int s0 = srcb[e];
        int s1 = srcb[e + 1];
        float4 pa = ((const float4*)(P + (size_t)s0 * HDIM))[lane];
        float4 pb = ((const float4*)(P + (size_t)s1 * HDIM))[lane];
        acc.x += fmaxf(pa.x + q.x, 0.f) + fmaxf(pb.x + q.x, 0.f);
        acc.y += fmaxf(pa.y + q.y, 0.f) + fmaxf(pb.y + q.y, 0.f);
        acc.z += fmaxf(pa.z + q.z, 0.f) + fmaxf(pb.z + q.z, 0.f);
        acc.w += fmaxf(pa.w + q.w, 0.f) + fmaxf(pb.w + q.w, 0.f);
    }
    if (e < e1) {
        int s0 = srcb[e];
        float4 pa = ((const float4*)(P + (size_t)s0 * HDIM))[lane];
        acc.x += fmaxf(pa.x + q.x, 0.f);
        acc.y += fmaxf(pa.y + q.y, 0.f);
        acc.z += fmaxf(pa.z + q.z, 0.f);
        acc.w += fmaxf(pa.w + q.w, 0.f);
    }
    ((float4*)(Hag + (size_t)w * HDIM))[lane] = acc;
}

// ---------------------------------------------------------------------------
// Kernel 4: msg = Hag @ msg_W2 + deg ⊗ b2
// ---------------------------------------------------------------------------
__global__ __launch_bounds__(256) void k_msg(const float* __restrict__ Hag,
                                             const float* __restrict__ W2,
                                             const float* __restrict__ b2,
                                             const int* __restrict__ deg,
                                             float* __restrict__ msg) {
    __shared__ float hs[16][HDIM];
    int j = threadIdx.x;
    int n0 = blockIdx.x * 16;
    for (int idx = j; idx < 16 * HDIM; idx += 256) {
        int r = idx >> 8, c = idx & 255;
        hs[r][c] = Hag[(size_t)(n0 + r) * HDIM + c];
    }
    __syncthreads();
    float acc[16];
    float bb = b2[j];
    #pragma unroll
    for (int r = 0; r < 16; ++r) acc[r] = (float)deg[n0 + r] * bb;
    for (int k = 0; k < HDIM; ++k) {
        float w = W2[(size_t)k * HDIM + j];
        #pragma unroll
        for (int r = 0; r < 16; ++r) acc[r] = fmaf(hs[r][k], w, acc[r]);
    }
    #pragma unroll
    for (int r = 0; r < 16; ++r) msg[(size_t)(n0 + r) * HDIM + j] = acc[r];
}

// ---------------------------------------------------------------------------
// Kernel 5: flash-style block-diagonal attention.
// Block = 4 waves; each wave owns 4 query rows (state in registers).
// K staged in 64-row LDS tiles, online softmax across tiles. All fp32.
// attn[i] = xq[i] - softmax_row(xq_b @ xk_b^T) @ xk_b
// ---------------------------------------------------------------------------
#define KT 64
__global__ __launch_bounds__(256) void k_attn(const float* __restrict__ xq,
                                              const float* __restrict__ xk,
                                              const int* __restrict__ offsq,
                                              const int* __restrict__ offsk,
                                              float* __restrict__ attn) {
    __shared__ float Ks[KT][130];        // +2 pad: conflict-free, b64-aligned
    __shared__ float qs_[4][4][DFEAT];
    __shared__ float pw[4][4][KT];
    int b = blockIdx.x;
    int q0 = offsq[b], q1 = offsq[b + 1];
    int k0 = offsk[b], k1 = offsk[b + 1];
    int nk = k1 - k0;
    int w = threadIdx.x >> 6, lane = threadIdx.x & 63;
    int t = threadIdx.x;

    for (int qs0 = q0 + blockIdx.y * 16; qs0 < q1; qs0 += gridDim.y * 16) {
        // stage this wave's 4 query rows (zero-fill invalid rows)
        #pragma unroll
        for (int r = 0; r < 4; ++r) {
            int row = qs0 + w * 4 + r;
            float2 v = make_float2(0.f, 0.f);
            if (row < q1) v = *(const float2*)&xq[(size_t)row * DFEAT + 2 * lane];
            *(float2*)&qs_[w][r][2 * lane] = v;
        }
        float mM[4], lL[4], oA[4], oB[4];
        #pragma unroll
        for (int r = 0; r < 4; ++r) { mM[r] = -1e30f; lL[r] = 0.f; oA[r] = 0.f; oB[r] = 0.f; }

        for (int t0 = 0; t0 < nk; t0 += KT) {
            int kt = min(KT, nk - t0);
            __syncthreads();   // previous tile fully consumed by all waves
            for (int idx = t; idx < kt * 64; idx += 256) {
                int row = idx >> 6, col = (idx & 63) * 2;
                float2 v = *(const float2*)&xk[(size_t)(k0 + t0 + row) * DFEAT + col];
                *(float2*)&Ks[row][col] = v;
            }
            __syncthreads();

            // scores: lane owns key c = lane (masked to kt)
            float sS[4];
            #pragma unroll
            for (int r = 0; r < 4; ++r) sS[r] = 0.f;
            #pragma unroll 8
            for (int d = 0; d < DFEAT; d += 2) {
                float2 kv = *(const float2*)&Ks[lane][d];
                #pragma unroll
                for (int r = 0; r < 4; ++r) {
                    float2 qv = *(const float2*)&qs_[w][r][d];
                    sS[r] = fmaf(kv.x, qv.x, fmaf(kv.y, qv.y, sS[r]));
                }
            }
            bool act = lane < kt;
            // online softmax update per row
            #pragma unroll
            for (int r = 0; r < 4; ++r) {
                float sv = act ? sS[r] : -1e30f;
                float tm = sv;
                #pragma unroll
                for (int off = 32; off; off >>= 1) tm = fmaxf(tm, __shfl_xor(tm, off));
                float nm = fmaxf(mM[r], tm);
                float sc = __expf(mM[r] - nm);
                float p  = act ? __expf(sS[r] - nm) : 0.f;
                float ps = p;
                #pragma unroll
                for (int off = 32; off; off >>= 1) ps += __shfl_xor(ps, off);
                lL[r] = lL[r] * sc + ps;
                oA[r] *= sc;
                oB[r] *= sc;
                mM[r] = nm;
                pw[w][r][lane] = p;
            }
            // PV: lane owns dims {lane, lane+64}
            for (int c = 0; c < kt; ++c) {
                float ka = Ks[c][lane];
                float kb = Ks[c][64 + lane];
                #pragma unroll
                for (int r = 0; r < 4; ++r) {
                    float pr = pw[w][r][c];
                    oA[r] = fmaf(pr, ka, oA[r]);
                    oB[r] = fmaf(pr, kb, oB[r]);
                }
            }
        }
        // write outputs
        #pragma unroll
        for (int r = 0; r < 4; ++r) {
            int row = qs0 + w * 4 + r;
            if (row < q1) {
                float inv = (lL[r] > 0.f) ? 1.0f / lL[r] : 0.f;
                attn[(size_t)row * DFEAT + lane] =
                    xq[(size_t)row * DFEAT + lane] - oA[r] * inv;
                attn[(size_t)row * DFEAT + 64 + lane] =
                    xq[(size_t)row * DFEAT + 64 + lane] - oB[r] * inv;
            }
        }
        __syncthreads();   // protect Ks before next chunk restages
    }
}

// ---------------------------------------------------------------------------
// Kernel 6: fused node update:
// out = x + relu([msg, attn, x] @ upd_W1 + upd_b1) @ upd_W2 + upd_b2
// ---------------------------------------------------------------------------
__global__ __launch_bounds__(256) void k_update(const float* __restrict__ x,
                                                const float* __restrict__ msg,
                                                const float* __restrict__ attn,
                                                const float* __restrict__ W1,
                                                const float* __restrict__ b1,
                                                const float* __restrict__ W2,
                                                const float* __restrict__ b2,
                                                float* __restrict__ out) {
    __shared__ float us[16][512];
    __shared__ float hs[16][HDIM];
    int j = threadIdx.x;
    int n0 = blockIdx.x * 16;
    for (int idx = j; idx < 16 * 512; idx += 256) {
        int r = idx >> 9, c = idx & 511;
        int node = n0 + r;
        float v;
        if (c < 256)      v = msg[(size_t)node * HDIM + c];
        else if (c < 384) v = attn[(size_t)node * DFEAT + (c - 256)];
        else              v = x[(size_t)node * DFEAT + (c - 384)];
        us[r][c] = v;
    }
    __syncthreads();
    float acc[16];
    float bb = b1[j];
    #pragma unroll
    for (int r = 0; r < 16; ++r) acc[r] = bb;
    for (int k = 0; k < 512; ++k) {
        float w = W1[(size_t)k * HDIM + j];
        #pragma unroll
        for (int r = 0; r < 16; ++r) acc[r] = fmaf(us[r][k], w, acc[r]);
    }
    #pragma unroll
    for (int r = 0; r < 16; ++r) hs[r][j] = fmaxf(acc[r], 0.f);
    __syncthreads();
    int c = j & 127, g = j >> 7;
    float acc2[8];
    float b2v = b2[c];
    #pragma unroll
    for (int r = 0; r < 8; ++r) acc2[r] = b2v;
    for (int k = 0; k < HDIM; ++k) {
        float w = W2[(size_t)k * DFEAT + c];
        #pragma unroll
        for (int r = 0; r < 8; ++r) acc2[r] = fmaf(hs[g * 8 + r][k], w, acc2[r]);
    }
    #pragma unroll
    for (int r = 0; r < 8; ++r) {
        int node = n0 + g * 8 + r;
        out[(size_t)node * DFEAT + c] = x[(size_t)node * DFEAT + c] + acc2[r];
    }
}

// ---------------------------------------------------------------------------
extern "C" void kernel_launch(void* const* d_in, const int* in_sizes, int n_in,
                              void* d_out, int out_size, void* d_ws, size_t ws_size,
                              hipStream_t stream) {
    const float* x1     = (const float*)d_in[0];
    const int*   ei1    = (const int*)d_in[1];
    const int*   batch1 = (const int*)d_in[2];
    const float* x2     = (const float*)d_in[3];
    const int*   ei2    = (const int*)d_in[4];
    const int*   batch2 = (const int*)d_in[5];
    const float* msg_W1 = (const float*)d_in[6];
    const float* msg_b1 = (const float*)d_in[7];
    const float* msg_W2 = (const float*)d_in[8];
    const float* msg_b2 = (const float*)d_in[9];
    const float* upd_W1 = (const float*)d_in[10];
    const float* upd_b1 = (const float*)d_in[11];
    const float* upd_W2 = (const float*)d_in[12];
    const float* upd_b2 = (const float*)d_in[13];

    const int N = in_sizes[0] / DFEAT;   // 8192
    const int E = in_sizes[1] / 2;       // 131072

    char* base = (char*)d_ws;
    int* offs1   = (int*)base;                 // 65
    int* offs2   = offs1 + 128;                // 65
    int* deg1    = offs2 + 128;                // N
    int* deg2    = deg1 + N;                   // N
    int* coffs1  = deg2 + N;                   // N+1
    int* coffs2  = coffs1 + (N + 64);          // N+1
    int* cur1    = coffs2 + (N + 64);          // N
    int* cur2    = cur1 + N;                   // N
    int* srcb1   = cur2 + N;                   // E
    int* srcb2   = srcb1 + E;                  // E
    float* F = (float*)(srcb2 + E);
    size_t NH = (size_t)N * HDIM;
    size_t ND = (size_t)N * DFEAT;
    float* P1    = F;
    float* Q1    = P1 + NH;
    float* P2    = Q1 + NH;
    float* Q2    = P2 + NH;
    float* msg1  = Q2 + NH;
    float* msg2  = msg1 + NH;
    float* attn1 = msg2 + NH;
    float* attn2 = attn1 + ND;
    float* Hag1  = attn2 + ND;
    float* Hag2  = Hag1 + NH;

    hipMemsetAsync(deg1, 0, 2 * (size_t)N * sizeof(int), stream);

    k_offsets<<<1, 192, 0, stream>>>(batch1, batch2, N, offs1, offs2);

    k_hist<<<(2 * E + 255) / 256, 256, 0, stream>>>(ei1, ei2, E, deg1, deg2);
    k_scan<<<2, 256, 0, stream>>>(deg1, deg2, N, coffs1, cur1, coffs2, cur2);
    k_scatter<<<(2 * E + 255) / 256, 256, 0, stream>>>(ei1, ei2, E, cur1, srcb1, cur2, srcb2);

    k_pq<<<N / 16, 256, 0, stream>>>(x1, msg_W1, msg_b1, P1, Q1);
    k_pq<<<N / 16, 256, 0, stream>>>(x2, msg_W1, msg_b1, P2, Q2);

    k_aggr<<<N / 4, 256, 0, stream>>>(P1, Q1, coffs1, srcb1, Hag1, N);
    k_aggr<<<N / 4, 256, 0, stream>>>(P2, Q2, coffs2, srcb2, Hag2, N);

    k_msg<<<N / 16, 256, 0, stream>>>(Hag1, msg_W2, msg_b2, deg1, msg1);
    k_msg<<<N / 16, 256, 0, stream>>>(Hag2, msg_W2, msg_b2, deg2, msg2);

    dim3 ag(64, 12);
    k_attn<<<ag, 256, 0, stream>>>(x1, x2, offs1, offs2, attn1);
    k_attn<<<ag, 256, 0, stream>>>(x2, x1, offs2, offs1, attn2);

    float* out1 = (float*)d_out;
    float* out2 = out1 + ND;
    k_update<<<N / 16, 256, 0, stream>>>(x1, msg1, attn1, upd_W1, upd_b1, upd_W2, upd_b2, out1);
    k_update<<<N / 16, 256, 0, stream>>>(x2, msg2, attn2, upd_W1, upd_b1, upd_W2, upd_b2, out2);
}

// Round 4
// 326.721 us; speedup vs baseline: 4.4437x; 1.4442x over previous
//
#include <hip/hip_runtime.h>
#include <math.h>

#define DFEAT 128
#define HDIM 256

typedef __attribute__((ext_vector_type(8))) short short8b;   // 8 bf16
typedef __attribute__((ext_vector_type(4))) short short4b;   // 4 bf16
typedef __attribute__((ext_vector_type(4))) float f32x4;

__device__ inline short f2bf(float f) {
    union { float f; unsigned u; } v; v.f = f;
    unsigned r = (v.u + 0x7fff + ((v.u >> 16) & 1)) >> 16;   // RNE
    return (short)r;
}

// ---------------------------------------------------------------------------
// Kernel 1: batch segment offsets via binary search (batch arrays are sorted).
// ---------------------------------------------------------------------------
__global__ void k_offsets(const int* __restrict__ batch1,
                          const int* __restrict__ batch2,
                          int n, int* __restrict__ offs1, int* __restrict__ offs2) {
    int t = threadIdx.x;
    if (t >= 130) return;
    const int* batch = (t < 65) ? batch1 : batch2;
    int b = (t < 65) ? t : t - 65;
    int lo = 0, hi = n;
    while (lo < hi) {
        int mid = (lo + hi) >> 1;
        if (batch[mid] < b) lo = mid + 1; else hi = mid;
    }
    if (t < 65) offs1[b] = lo; else offs2[b] = lo;
}

// ---------------------------------------------------------------------------
// Weight cast+transpose to bf16 (K-contiguous rows for MFMA B-fragments).
//   WpqT[512][128]  : j<256 -> msg_W1[k][j] ; j>=256 -> msg_W1[128+k][j-256]
//   bias_pq[512]    : msg_b1 | 0
//   WmsgT[256][256] : msg_W2[k][j]
//   Wu1T[256][512]  : upd_W1[k][j]
//   Wu2T[128][256]  : upd_W2[k][j]
// ---------------------------------------------------------------------------
__global__ __launch_bounds__(256) void k_castw(const float* __restrict__ msg_W1,
                                               const float* __restrict__ msg_b1,
                                               const float* __restrict__ msg_W2,
                                               const float* __restrict__ upd_W1,
                                               const float* __restrict__ upd_W2,
                                               short* __restrict__ WpqT,
                                               float* __restrict__ bias_pq,
                                               short* __restrict__ WmsgT,
                                               short* __restrict__ Wu1T,
                                               short* __restrict__ Wu2T) {
    int t = blockIdx.x * 256 + threadIdx.x;
    if (t < 65536) {                                  // WpqT
        int j = t >> 7, k = t & 127;
        float v = (j < 256) ? msg_W1[(size_t)k * 256 + j]
                            : msg_W1[(size_t)(128 + k) * 256 + (j - 256)];
        WpqT[t] = f2bf(v);
        return;
    }
    t -= 65536;
    if (t < 512) { bias_pq[t] = (t < 256) ? msg_b1[t] : 0.f; return; }
    t -= 512;
    if (t < 65536) {                                  // WmsgT
        int j = t >> 8, k = t & 255;
        WmsgT[t] = f2bf(msg_W2[(size_t)k * 256 + j]);
        return;
    }
    t -= 65536;
    if (t < 131072) {                                 // Wu1T
        int j = t >> 9, k = t & 511;
        Wu1T[t] = f2bf(upd_W1[(size_t)k * 256 + j]);
        return;
    }
    t -= 131072;
    if (t < 32768) {                                  // Wu2T
        int j = t >> 8, k = t & 255;
        Wu2T[t] = f2bf(upd_W2[(size_t)k * 128 + j]);
    }
}

// ---------------------------------------------------------------------------
// x -> bf16 cast (both graphs), float4 -> 4xbf16 per thread.
// ---------------------------------------------------------------------------
__global__ __launch_bounds__(256) void k_castx(const float* __restrict__ x1,
                                               const float* __restrict__ x2,
                                               short* __restrict__ xb1,
                                               short* __restrict__ xb2, int nq) {
    int t = blockIdx.x * 256 + threadIdx.x;           // nq = N*DFEAT/4 per graph
    const float* x; short* o;
    if (t < nq) { x = x1; o = xb1; } else if (t < 2 * nq) { x = x2; o = xb2; t -= nq; }
    else return;
    float4 v = ((const float4*)x)[t];
    short4b s; s.x = f2bf(v.x); s.y = f2bf(v.y); s.z = f2bf(v.z); s.w = f2bf(v.w);
    ((short4b*)o)[t] = s;
}

// ---------------------------------------------------------------------------
// MFMA GEMM: PQ[8192][512] = x_bf[8192][128] @ Wpq[128][512] + bias_pq  (fp32 out)
// Block: 256 thr / 4 waves; 32 rows per block; wave = 16 rows x 256 cols.
// ---------------------------------------------------------------------------
__global__ __launch_bounds__(256) void k_pq_mfma(const short* __restrict__ xb1,
                                                 const short* __restrict__ xb2,
                                                 const short* __restrict__ WpqT,
                                                 const float* __restrict__ bias,
                                                 float* __restrict__ PQ1,
                                                 float* __restrict__ PQ2, int nblk) {
    int blk = blockIdx.x;
    const short* A; float* C;
    if (blk < nblk) { A = xb1; C = PQ1; } else { A = xb2; C = PQ2; blk -= nblk; }
    int w = threadIdx.x >> 6, l = threadIdx.x & 63;
    int row0 = blk * 32 + (w & 1) * 16;
    int ct0 = (w >> 1) * 16;                 // 16 col-tiles per wave (of 32)
    int lm = l & 15, kg = (l >> 4) * 8;
    const short* Ar = A + (size_t)(row0 + lm) * 128 + kg;
    short8b a[4];
    #pragma unroll
    for (int ks = 0; ks < 4; ++ks) a[ks] = *(const short8b*)(Ar + ks * 32);
    for (int ct = ct0; ct < ct0 + 16; ++ct) {
        f32x4 acc = {0.f, 0.f, 0.f, 0.f};
        const short* Br = WpqT + (size_t)(ct * 16 + lm) * 128 + kg;
        #pragma unroll
        for (int ks = 0; ks < 4; ++ks) {
            short8b b = *(const short8b*)(Br + ks * 32);
            acc = __builtin_amdgcn_mfma_f32_16x16x32_bf16(a[ks], b, acc, 0, 0, 0);
        }
        int col = ct * 16 + lm;
        float bv = bias[col];
        #pragma unroll
        for (int j = 0; j < 4; ++j) {
            int r = row0 + (l >> 4) * 4 + j;
            C[(size_t)r * 512 + col] = acc[j] + bv;
        }
    }
}

// ---------------------------------------------------------------------------
// Kernel 3a/3b/3c: CSR build (hist, scan, scatter) — unchanged.
// ---------------------------------------------------------------------------
__global__ __launch_bounds__(256) void k_hist(const int* __restrict__ ei1,
                                              const int* __restrict__ ei2, int E,
                                              int* __restrict__ deg1, int* __restrict__ deg2) {
    int t = blockIdx.x * 256 + threadIdx.x;
    if (t < E) atomicAdd(deg1 + ei1[t], 1);
    else if (t < 2 * E) atomicAdd(deg2 + ei2[t - E], 1);
}

__global__ __launch_bounds__(256) void k_scan(const int* __restrict__ deg1,
                                              const int* __restrict__ deg2, int N,
                                              int* __restrict__ offs1, int* __restrict__ cur1,
                                              int* __restrict__ offs2, int* __restrict__ cur2) {
    const int* deg = blockIdx.x ? deg2 : deg1;
    int* offs = blockIdx.x ? offs2 : offs1;
    int* cur  = blockIdx.x ? cur2  : cur1;
    int t = threadIdx.x;
    int base = t * 32;
    int vals[32];
    int run = 0;
    #pragma unroll
    for (int i = 0; i < 32; ++i) { vals[i] = run; run += deg[base + i]; }
    __shared__ int tot[256];
    tot[t] = run;
    __syncthreads();
    for (int off = 1; off < 256; off <<= 1) {
        int v = (t >= off) ? tot[t - off] : 0;
        __syncthreads();
        tot[t] += v;
        __syncthreads();
    }
    int prefix = (t == 0) ? 0 : tot[t - 1];
    #pragma unroll
    for (int i = 0; i < 32; ++i) {
        int o = prefix + vals[i];
        offs[base + i] = o;
        cur[base + i] = o;
    }
    if (t == 255) offs[N] = tot[255];
}

__global__ __launch_bounds__(256) void k_scatter(const int* __restrict__ ei1,
                                                 const int* __restrict__ ei2, int E,
                                                 int* __restrict__ cur1, int* __restrict__ srcb1,
                                                 int* __restrict__ cur2, int* __restrict__ srcb2) {
    int t = blockIdx.x * 256 + threadIdx.x;
    if (t < E) {
        int tgt = ei1[t], src = ei1[E + t];
        srcb1[atomicAdd(cur1 + tgt, 1)] = src;
    } else if (t < 2 * E) {
        int e = t - E;
        int tgt = ei2[e], src = ei2[E + e];
        srcb2[atomicAdd(cur2 + tgt, 1)] = src;
    }
}

// ---------------------------------------------------------------------------
// Kernel 3d: gather-aggregate; PQ layout [node][512] (P=cols 0-255, Q=256-511).
// Writes Hag as bf16 (A-operand of the msg GEMM).
// ---------------------------------------------------------------------------
__global__ __launch_bounds__(256) void k_aggr(const float* __restrict__ PQ,
                                              const int* __restrict__ offs,
                                              const int* __restrict__ srcb,
                                              short* __restrict__ Hag, int N) {
    int w = (blockIdx.x * 256 + threadIdx.x) >> 6;
    int lane = threadIdx.x & 63;
    if (w >= N) return;
    float4 q = *(const float4*)(PQ + (size_t)w * 512 + 256 + lane * 4);
    int e0 = offs[w], e1 = offs[w + 1];
    float4 acc = {0.f, 0.f, 0.f, 0.f};
    int e = e0;
    for (; e + 1 < e1; e += 2) {
        int s0 = srcb[e];
        int s1 = srcb[e + 1];
        float4 pa = *(const float4*)(PQ + (size_t)s0 * 512 + lane * 4);
        float4 pb = *(const float4*)(PQ + (size_t)s1 * 512 + lane * 4);
        acc.x += fmaxf(pa.x + q.x, 0.f) + fmaxf(pb.x + q.x, 0.f);
        acc.y += fmaxf(pa.y + q.y, 0.f) + fmaxf(pb.y + q.y, 0.f);
        acc.z += fmaxf(pa.z + q.z, 0.f) + fmaxf(pb.z + q.z, 0.f);
        acc.w += fmaxf(pa.w + q.w, 0.f) + fmaxf(pb.w + q.w, 0.f);
    }
    if (e < e1) {
        int s0 = srcb[e];
        float4 pa = *(const float4*)(PQ + (size_t)s0 * 512 + lane * 4);
        acc.x += fmaxf(pa.x + q.x, 0.f);
        acc.y += fmaxf(pa.y + q.y, 0.f);
        acc.z += fmaxf(pa.z + q.z, 0.f);
        acc.w += fmaxf(pa.w + q.w, 0.f);
    }
    short4b o;
    o.x = f2bf(acc.x); o.y = f2bf(acc.y); o.z = f2bf(acc.z); o.w = f2bf(acc.w);
    ((short4b*)(Hag + (size_t)w * HDIM))[lane] = o;
}

// ---------------------------------------------------------------------------
// MFMA GEMM: msg = Hag_bf @ msg_W2 + deg*b2 -> bf16 into U cols 0..255.
// ---------------------------------------------------------------------------
__global__ __launch_bounds__(256) void k_msg_mfma(const short* __restrict__ Hag1,
                                                  const short* __restrict__ Hag2,
                                                  const short* __restrict__ WmsgT,
                                                  const float* __restrict__ b2,
                                                  const int* __restrict__ deg1,
                                                  const int* __restrict__ deg2,
                                                  short* __restrict__ U1,
                                                  short* __restrict__ U2, int nblk) {
    int blk = blockIdx.x;
    const short* A; short* U; const int* deg;
    if (blk < nblk) { A = Hag1; U = U1; deg = deg1; }
    else { A = Hag2; U = U2; deg = deg2; blk -= nblk; }
    int w = threadIdx.x >> 6, l = threadIdx.x & 63;
    int row0 = blk * 32 + (w & 1) * 16;
    int ct0 = (w >> 1) * 8;                  // 8 col-tiles per wave (of 16)
    int lm = l & 15, kg = (l >> 4) * 8;
    const short* Ar = A + (size_t)(row0 + lm) * 256 + kg;
    short8b a[8];
    #pragma unroll
    for (int ks = 0; ks < 8; ++ks) a[ks] = *(const short8b*)(Ar + ks * 32);
    float dg[4];
    #pragma unroll
    for (int j = 0; j < 4; ++j) dg[j] = (float)deg[row0 + (l >> 4) * 4 + j];
    for (int ct = ct0; ct < ct0 + 8; ++ct) {
        f32x4 acc = {0.f, 0.f, 0.f, 0.f};
        const short* Br = WmsgT + (size_t)(ct * 16 + lm) * 256 + kg;
        #pragma unroll
        for (int ks = 0; ks < 8; ++ks) {
            short8b b = *(const short8b*)(Br + ks * 32);
            acc = __builtin_amdgcn_mfma_f32_16x16x32_bf16(a[ks], b, acc, 0, 0, 0);
        }
        int col = ct * 16 + lm;
        float bv = b2[col];
        #pragma unroll
        for (int j = 0; j < 4; ++j) {
            int r = row0 + (l >> 4) * 4 + j;
            U[(size_t)r * 512 + col] = f2bf(acc[j] + dg[j] * bv);
        }
    }
}

// ---------------------------------------------------------------------------
// Kernel 5: flash-style block-diagonal attention (fp32). Writes attn AND x
// as bf16 into U cols 256..511.
// ---------------------------------------------------------------------------
#define KT 64
__global__ __launch_bounds__(256) void k_attn(const float* __restrict__ xq,
                                              const float* __restrict__ xk,
                                              const int* __restrict__ offsq,
                                              const int* __restrict__ offsk,
                                              short* __restrict__ U) {
    __shared__ float Ks[KT][130];
    __shared__ float qs_[4][4][DFEAT];
    __shared__ float pw[4][4][KT];
    int b = blockIdx.x;
    int q0 = offsq[b], q1 = offsq[b + 1];
    int k0 = offsk[b], k1 = offsk[b + 1];
    int nk = k1 - k0;
    int w = threadIdx.x >> 6, lane = threadIdx.x & 63;
    int t = threadIdx.x;

    for (int qs0 = q0 + blockIdx.y * 16; qs0 < q1; qs0 += gridDim.y * 16) {
        #pragma unroll
        for (int r = 0; r < 4; ++r) {
            int row = qs0 + w * 4 + r;
            float2 v = make_float2(0.f, 0.f);
            if (row < q1) v = *(const float2*)&xq[(size_t)row * DFEAT + 2 * lane];
            *(float2*)&qs_[w][r][2 * lane] = v;
        }
        float mM[4], lL[4], oA[4], oB[4];
        #pragma unroll
        for (int r = 0; r < 4; ++r) { mM[r] = -1e30f; lL[r] = 0.f; oA[r] = 0.f; oB[r] = 0.f; }

        for (int t0 = 0; t0 < nk; t0 += KT) {
            int kt = min(KT, nk - t0);
            __syncthreads();
            for (int idx = t; idx < kt * 64; idx += 256) {
                int row = idx >> 6, col = (idx & 63) * 2;
                float2 v = *(const float2*)&xk[(size_t)(k0 + t0 + row) * DFEAT + col];
                *(float2*)&Ks[row][col] = v;
            }
            __syncthreads();

            float sS[4];
            #pragma unroll
            for (int r = 0; r < 4; ++r) sS[r] = 0.f;
            #pragma unroll 8
            for (int d = 0; d < DFEAT; d += 2) {
                float2 kv = *(const float2*)&Ks[lane][d];
                #pragma unroll
                for (int r = 0; r < 4; ++r) {
                    float2 qv = *(const float2*)&qs_[w][r][d];
                    sS[r] = fmaf(kv.x, qv.x, fmaf(kv.y, qv.y, sS[r]));
                }
            }
            bool act = lane < kt;
            #pragma unroll
            for (int r = 0; r < 4; ++r) {
                float sv = act ? sS[r] : -1e30f;
                float tm = sv;
                #pragma unroll
                for (int off = 32; off; off >>= 1) tm = fmaxf(tm, __shfl_xor(tm, off));
                float nm = fmaxf(mM[r], tm);
                float sc = __expf(mM[r] - nm);
                float p  = act ? __expf(sS[r] - nm) : 0.f;
                float ps = p;
                #pragma unroll
                for (int off = 32; off; off >>= 1) ps += __shfl_xor(ps, off);
                lL[r] = lL[r] * sc + ps;
                oA[r] *= sc;
                oB[r] *= sc;
                mM[r] = nm;
                pw[w][r][lane] = p;
            }
            for (int c = 0; c < kt; ++c) {
                float ka = Ks[c][lane];
                float kb = Ks[c][64 + lane];
                #pragma unroll
                for (int r = 0; r < 4; ++r) {
                    float pr = pw[w][r][c];
                    oA[r] = fmaf(pr, ka, oA[r]);
                    oB[r] = fmaf(pr, kb, oB[r]);
                }
            }
        }
        #pragma unroll
        for (int r = 0; r < 4; ++r) {
            int row = qs0 + w * 4 + r;
            if (row < q1) {
                float inv = (lL[r] > 0.f) ? 1.0f / lL[r] : 0.f;
                float x0 = xq[(size_t)row * DFEAT + lane];
                float x1 = xq[(size_t)row * DFEAT + 64 + lane];
                size_t ub = (size_t)row * 512;
                U[ub + 256 + lane] = f2bf(x0 - oA[r] * inv);
                U[ub + 320 + lane] = f2bf(x1 - oB[r] * inv);
                U[ub + 384 + lane] = f2bf(x0);
                U[ub + 448 + lane] = f2bf(x1);
            }
        }
        __syncthreads();
    }
}

// ---------------------------------------------------------------------------
// MFMA fused update: out = x + relu(U@Wu1 + b1) @ Wu2 + b2.
// 32 rows/block; layer-1 H staged in LDS as bf16 [32][264] (pad vs conflicts).
// ---------------------------------------------------------------------------
__global__ __launch_bounds__(256) void k_upd_mfma(const short* __restrict__ U1,
                                                  const short* __restrict__ U2,
                                                  const float* __restrict__ x1,
                                                  const float* __restrict__ x2,
                                                  const short* __restrict__ Wu1T,
                                                  const short* __restrict__ Wu2T,
                                                  const float* __restrict__ b1,
                                                  const float* __restrict__ b2,
                                                  float* __restrict__ out1,
                                                  float* __restrict__ out2, int nblk) {
    __shared__ short Hs[32][264];
    int blk = blockIdx.x;
    const short* Up; const float* x; float* out;
    if (blk < nblk) { Up = U1; x = x1; out = out1; }
    else { Up = U2; x = x2; out = out2; blk -= nblk; }
    int w = threadIdx.x >> 6, l = threadIdx.x & 63;
    int rw = (w & 1) * 16;                    // wave's row block within the 32
    int row0 = blk * 32 + rw;
    int lm = l & 15, kg = (l >> 4) * 8;

    // layer 1: 16 rows x 128 cols per wave (col half by w>>1)
    int ct0 = (w >> 1) * 8;
    const short* Ar = Up + (size_t)(row0 + lm) * 512 + kg;
    short8b a[16];
    #pragma unroll
    for (int ks = 0; ks < 16; ++ks) a[ks] = *(const short8b*)(Ar + ks * 32);
    for (int ct = ct0; ct < ct0 + 8; ++ct) {
        f32x4 acc = {0.f, 0.f, 0.f, 0.f};
        const short* Br = Wu1T + (size_t)(ct * 16 + lm) * 512 + kg;
        #pragma unroll
        for (int ks = 0; ks < 16; ++ks) {
            short8b b = *(const short8b*)(Br + ks * 32);
            acc = __builtin_amdgcn_mfma_f32_16x16x32_bf16(a[ks], b, acc, 0, 0, 0);
        }
        int col = ct * 16 + lm;
        float bv = b1[col];
        #pragma unroll
        for (int j = 0; j < 4; ++j) {
            int r = rw + (l >> 4) * 4 + j;
            Hs[r][col] = f2bf(fmaxf(acc[j] + bv, 0.f));
        }
    }
    __syncthreads();

    // layer 2: 16 rows x 64 cols per wave (col half by w>>1), K=256
    int ct20 = (w >> 1) * 4;
    short8b a2[8];
    #pragma unroll
    for (int ks = 0; ks < 8; ++ks)
        a2[ks] = *(const short8b*)&Hs[rw + lm][ks * 32 + kg];
    for (int ct = ct20; ct < ct20 + 4; ++ct) {
        f32x4 acc = {0.f, 0.f, 0.f, 0.f};
        const short* Br = Wu2T + (size_t)(ct * 16 + lm) * 256 + kg;
        #pragma unroll
        for (int ks = 0; ks < 8; ++ks) {
            short8b b = *(const short8b*)(Br + ks * 32);
            acc = __builtin_amdgcn_mfma_f32_16x16x32_bf16(a2[ks], b, acc, 0, 0, 0);
        }
        int col = ct * 16 + lm;
        float bv = b2[col];
        #pragma unroll
        for (int j = 0; j < 4; ++j) {
            int r = row0 + (l >> 4) * 4 + j;
            out[(size_t)r * DFEAT + col] = x[(size_t)r * DFEAT + col] + acc[j] + bv;
        }
    }
}

// ---------------------------------------------------------------------------
extern "C" void kernel_launch(void* const* d_in, const int* in_sizes, int n_in,
                              void* d_out, int out_size, void* d_ws, size_t ws_size,
                              hipStream_t stream) {
    const float* x1     = (const float*)d_in[0];
    const int*   ei1    = (const int*)d_in[1];
    const int*   batch1 = (const int*)d_in[2];
    const float* x2     = (const float*)d_in[3];
    const int*   ei2    = (const int*)d_in[4];
    const int*   batch2 = (const int*)d_in[5];
    const float* msg_W1 = (const float*)d_in[6];
    const float* msg_b1 = (const float*)d_in[7];
    const float* msg_W2 = (const float*)d_in[8];
    const float* msg_b2 = (const float*)d_in[9];
    const float* upd_W1 = (const float*)d_in[10];
    const float* upd_b1 = (const float*)d_in[11];
    const float* upd_W2 = (const float*)d_in[12];
    const float* upd_b2 = (const float*)d_in[13];

    const int N = in_sizes[0] / DFEAT;   // 8192
    const int E = in_sizes[1] / 2;       // 131072

    char* base = (char*)d_ws;
    int* offs1   = (int*)base;                 // 128
    int* offs2   = offs1 + 128;                // 128
    int* deg1    = offs2 + 128;                // N
    int* deg2    = deg1 + N;                   // N
    int* coffs1  = deg2 + N;                   // N+64
    int* coffs2  = coffs1 + (N + 64);          // N+64
    int* cur1    = coffs2 + (N + 64);          // N
    int* cur2    = cur1 + N;                   // N
    int* srcb1   = cur2 + N;                   // E
    int* srcb2   = srcb1 + E;                  // E
    float* F = (float*)(srcb2 + E);
    size_t N512 = (size_t)N * 512;
    float* PQ1     = F;                        // N*512 f32
    float* PQ2     = PQ1 + N512;
    float* bias_pq = PQ2 + N512;               // 512
    short* S = (short*)(bias_pq + 512);
    short* xb1   = S;                          // N*128
    short* xb2   = xb1 + (size_t)N * 128;
    short* Hag1  = xb2 + (size_t)N * 128;      // N*256
    short* Hag2  = Hag1 + (size_t)N * 256;
    short* U1    = Hag2 + (size_t)N * 256;     // N*512
    short* U2    = U1 + N512;
    short* WpqT  = U2 + N512;                  // 512*128
    short* WmsgT = WpqT + 65536;               // 256*256
    short* Wu1T  = WmsgT + 65536;              // 256*512
    short* Wu2T  = Wu1T + 131072;              // 128*256

    hipMemsetAsync(deg1, 0, 2 * (size_t)N * sizeof(int), stream);

    k_offsets<<<1, 192, 0, stream>>>(batch1, batch2, N, offs1, offs2);
    k_hist<<<(2 * E + 255) / 256, 256, 0, stream>>>(ei1, ei2, E, deg1, deg2);
    k_scan<<<2, 256, 0, stream>>>(deg1, deg2, N, coffs1, cur1, coffs2, cur2);
    k_scatter<<<(2 * E + 255) / 256, 256, 0, stream>>>(ei1, ei2, E, cur1, srcb1, cur2, srcb2);

    k_castw<<<1154, 256, 0, stream>>>(msg_W1, msg_b1, msg_W2, upd_W1, upd_W2,
                                      WpqT, bias_pq, WmsgT, Wu1T, Wu2T);
    int nq = N * DFEAT / 4;
    k_castx<<<(2 * nq + 255) / 256, 256, 0, stream>>>(x1, x2, xb1, xb2, nq);

    int nblk = N / 32;   // 256
    k_pq_mfma<<<2 * nblk, 256, 0, stream>>>(xb1, xb2, WpqT, bias_pq, PQ1, PQ2, nblk);

    k_aggr<<<N / 4, 256, 0, stream>>>(PQ1, coffs1, srcb1, Hag1, N);
    k_aggr<<<N / 4, 256, 0, stream>>>(PQ2, coffs2, srcb2, Hag2, N);

    k_msg_mfma<<<2 * nblk, 256, 0, stream>>>(Hag1, Hag2, WmsgT, msg_b2,
                                             deg1, deg2, U1, U2, nblk);

    dim3 ag(64, 12);
    k_attn<<<ag, 256, 0, stream>>>(x1, x2, offs1, offs2, U1);
    k_attn<<<ag, 256, 0, stream>>>(x2, x1, offs2, offs1, U2);

    float* out1 = (float*)d_out;
    float* out2 = out1 + (size_t)N * DFEAT;
    k_upd_mfma<<<2 * nblk, 256, 0, stream>>>(U1, U2, x1, x2, Wu1T, Wu2T,
                                             upd_b1, upd_b2, out1, out2, nblk);
}